// Round 16
// baseline (193.707 us; speedup 1.0000x reference)
//
#include <hip/hip_runtime.h>

#define CELL 50.0f
#define N_TABLE 1024
#define NB 1024            // buckets of 128 atoms each (max 131072 atoms)
#define NBLK 512           // histogram/scatter blocks
#define THREADS 256
#define SCAT_THREADS 512
#define LBUF_CAP 25088     // max entries per scatter block (2*ppb)
#define RED_THREADS 512
#define PHASE_CAP 9216     // entries sorted per reduce phase (36.9 KB LDS)

typedef unsigned int uint;
typedef unsigned long long ull;

// ---------------- K0: pack q into float4 ----------------
__global__ __launch_bounds__(THREADS) void pack_q4_kernel(
    const float* __restrict__ q, float4* __restrict__ q4, int n_atoms)
{
    int i = blockIdx.x * THREADS + threadIdx.x;
    if (i < n_atoms)
        q4[i] = make_float4(q[3 * i], q[3 * i + 1], q[3 * i + 2], 0.0f);
}

// ---------------- K1: per-block bucket histogram (int4 loads) ----------------
__global__ __launch_bounds__(THREADS) void hist_kernel(
    const int2* __restrict__ nbr, uint* __restrict__ partial,
    uint* __restrict__ rawh, int n_pairs, int ppb)
{
    __shared__ uint h[NB];
    for (int k = threadIdx.x; k < NB; k += THREADS) h[k] = 0;
    __syncthreads();
    int start = blockIdx.x * ppb;                 // ppb even -> start even
    int end   = min(start + ppb, n_pairs & ~1);
    const int4* nbr4 = (const int4*)nbr;
    for (int p2 = (start >> 1) + threadIdx.x; p2 < (end >> 1); p2 += THREADS) {
        int4 v = nbr4[p2];
        atomicAdd(&h[((uint)v.x) >> 7], 1u);
        atomicAdd(&h[((uint)v.y) >> 7], 1u);
        atomicAdd(&h[((uint)v.z) >> 7], 1u);
        atomicAdd(&h[((uint)v.w) >> 7], 1u);
    }
    if (blockIdx.x == 0 && threadIdx.x == 0 && (n_pairs & 1)) {
        int2 ij = nbr[n_pairs - 1];
        atomicAdd(&h[((uint)ij.x) >> 7], 1u);
        atomicAdd(&h[((uint)ij.y) >> 7], 1u);
    }
    __syncthreads();
    for (int k = threadIdx.x; k < NB; k += THREADS) {
        uint c = h[k];
        partial[k * NBLK + blockIdx.x] = c;
        rawh[blockIdx.x * NB + k]      = c;
    }
}

// ---------------- K2a: per-bucket exclusive scan over block partials ----------------
__global__ __launch_bounds__(THREADS) void scan_rows_kernel(
    uint* __restrict__ partial, uint* __restrict__ binTotal)
{
    __shared__ uint s[THREADS];
    int bin = blockIdx.x;
    uint running = 0;
    for (int c = 0; c < NBLK / THREADS; c++) {
        int idx = bin * NBLK + c * THREADS + threadIdx.x;
        uint v = partial[idx];
        s[threadIdx.x] = v;
        __syncthreads();
        for (int off = 1; off < THREADS; off <<= 1) {
            uint t = (threadIdx.x >= (uint)off) ? s[threadIdx.x - off] : 0u;
            __syncthreads();
            s[threadIdx.x] += t;
            __syncthreads();
        }
        partial[idx] = running + s[threadIdx.x] - v;   // exclusive within bin
        uint csum = s[THREADS - 1];
        __syncthreads();
        running += csum;
    }
    if (threadIdx.x == 0) binTotal[bin] = running;
}

// ---------------- K2b: exclusive scan of bucket totals ----------------
__global__ __launch_bounds__(THREADS) void scan_totals_kernel(
    const uint* __restrict__ binTotal, uint* __restrict__ binBase)
{
    __shared__ uint s[THREADS];
    uint v[4];
    uint sum = 0;
    int base = threadIdx.x * 4;
    for (int k = 0; k < 4; k++) { v[k] = binTotal[base + k]; sum += v[k]; }
    s[threadIdx.x] = sum;
    __syncthreads();
    for (int off = 1; off < THREADS; off <<= 1) {
        uint t = (threadIdx.x >= (uint)off) ? s[threadIdx.x - off] : 0u;
        __syncthreads();
        s[threadIdx.x] += t;
        __syncthreads();
    }
    uint run = s[threadIdx.x] - sum;
    for (int k = 0; k < 4; k++) { binBase[base + k] = run; run += v[k]; }
    if (threadIdx.x == THREADS - 1) binBase[NB] = run;
}

// ---------------- K3: LDS-sorted scatter (coalesced run writes) ----------------
__global__ __launch_bounds__(SCAT_THREADS) void scatter_sorted_kernel(
    const int2* __restrict__ nbr, const uint* __restrict__ rawh,
    const uint* __restrict__ partial, const uint* __restrict__ binBase,
    uint* __restrict__ entries, int n_pairs, int ppb)
{
    __shared__ uint lbuf[LBUF_CAP];          // 100.4 KB
    __shared__ uint localBase[NB];           // 4 KB
    __shared__ uint lcur[NB];                // 4 KB
    __shared__ uint gcur[NB];                // 4 KB: prefetched global dst bases
    __shared__ uint ssc[SCAT_THREADS];       // 2 KB

    int tid = threadIdx.x;
    int blk = blockIdx.x;

    // prefetch global copy-out bases early (latency amortized once, 512-wide)
    for (int k = tid; k < NB; k += SCAT_THREADS)
        gcur[k] = binBase[k] + partial[k * NBLK + blk];

    // per-block histogram -> exclusive scan (2 buckets per thread)
    uint v0 = rawh[blk * NB + 2 * tid];
    uint v1 = rawh[blk * NB + 2 * tid + 1];
    uint sum2 = v0 + v1;
    ssc[tid] = sum2;
    __syncthreads();
    for (int off = 1; off < SCAT_THREADS; off <<= 1) {
        uint t = (tid >= off) ? ssc[tid - off] : 0u;
        __syncthreads();
        ssc[tid] += t;
        __syncthreads();
    }
    uint base = ssc[tid] - sum2;
    localBase[2 * tid]     = base;      lcur[2 * tid]     = base;
    localBase[2 * tid + 1] = base + v0; lcur[2 * tid + 1] = base + v0;
    __syncthreads();

    // bin entries into LDS (double-buffered loads, batched atomics)
    int start = blk * ppb;
    int end   = min(start + ppb, n_pairs & ~1);
    const int4* nbr4 = (const int4*)nbr;
    int lim = end >> 1;
    int p2  = (start >> 1) + tid;
    if (p2 < lim) {
        int4 v = nbr4[p2];
        for (;;) {
            int pn = p2 + SCAT_THREADS;
            int4 vnext;
            bool has = pn < lim;
            if (has) vnext = nbr4[pn];
            uint i0 = (uint)v.x, j0 = (uint)v.y, i1 = (uint)v.z, j1 = (uint)v.w;
            uint o0 = atomicAdd(&lcur[i0 >> 7], 1u);
            uint o1 = atomicAdd(&lcur[j0 >> 7], 1u);
            uint o2 = atomicAdd(&lcur[i1 >> 7], 1u);
            uint o3 = atomicAdd(&lcur[j1 >> 7], 1u);
            lbuf[o0] = (j0 << 7) | (i0 & 127u);
            lbuf[o1] = (i0 << 7) | (j0 & 127u);
            lbuf[o2] = (j1 << 7) | (i1 & 127u);
            lbuf[o3] = (i1 << 7) | (j1 & 127u);
            if (!has) break;
            v = vnext; p2 = pn;
        }
    }
    if (blk == 0 && tid == 0 && (n_pairs & 1)) {
        int2 ij = nbr[n_pairs - 1];
        uint i = (uint)ij.x, j = (uint)ij.y;
        uint o;
        o = atomicAdd(&lcur[i >> 7], 1u); lbuf[o] = (j << 7) | (i & 127u);
        o = atomicAdd(&lcur[j >> 7], 1u); lbuf[o] = (i << 7) | (j & 127u);
    }
    __syncthreads();

    // wave-per-bucket coalesced copy-out (gcur from LDS, no serial L2 reads)
    int wave = tid >> 6, lane = tid & 63;
    for (int b = wave; b < NB; b += SCAT_THREADS / 64) {
        uint lb  = localBase[b];
        uint cnt = lcur[b] - lb;
        if (!cnt) continue;
        uint gdst = gcur[b];
        for (uint o = lane; o < cnt; o += 64)
            entries[gdst + o] = lbuf[lb + o];
    }
}

// ---------------- K3-fallback: unsorted scatter (if LBUF too small) ----------------
__global__ __launch_bounds__(THREADS) void scatter_plain_kernel(
    const int2* __restrict__ nbr, const uint* __restrict__ partial,
    const uint* __restrict__ binBase, uint* __restrict__ entries,
    int n_pairs, int ppb)
{
    __shared__ uint cur[NB];
    for (int k = threadIdx.x; k < NB; k += THREADS)
        cur[k] = binBase[k] + partial[k * NBLK + blockIdx.x];
    __syncthreads();
    int start = blockIdx.x * ppb;
    int end   = min(start + ppb, n_pairs & ~1);
    const int4* nbr4 = (const int4*)nbr;
    for (int p2 = (start >> 1) + threadIdx.x; p2 < (end >> 1); p2 += THREADS) {
        int4 v = nbr4[p2];
        uint i0 = (uint)v.x, j0 = (uint)v.y, i1 = (uint)v.z, j1 = (uint)v.w;
        uint p;
        p = atomicAdd(&cur[i0 >> 7], 1u); entries[p] = (j0 << 7) | (i0 & 127u);
        p = atomicAdd(&cur[j0 >> 7], 1u); entries[p] = (i0 << 7) | (j0 & 127u);
        p = atomicAdd(&cur[i1 >> 7], 1u); entries[p] = (j1 << 7) | (i1 & 127u);
        p = atomicAdd(&cur[j1 >> 7], 1u); entries[p] = (i1 << 7) | (j1 & 127u);
    }
    if (blockIdx.x == 0 && threadIdx.x == 0 && (n_pairs & 1)) {
        int2 ij = nbr[n_pairs - 1];
        uint i = (uint)ij.x, j = (uint)ij.y;
        uint p;
        p = atomicAdd(&cur[i >> 7], 1u); entries[p] = (j << 7) | (i & 127u);
        p = atomicAdd(&cur[j >> 7], 1u); entries[p] = (i << 7) | (j & 127u);
    }
}

// ---------------- physics ----------------
__device__ __forceinline__ void phys_acc(
    float ax, float ay, float az, float ox, float oy, float oz,
    const float* __restrict__ tfa, const float* __restrict__ tfd,
    float r0, float inv_dr, float& fx, float& fy, float& fz)
{
    float dx = ax - ox, dy = ay - oy, dz = az - oz;
    // exact minimum image for d in (-50,50): round-half-even boundary at +/-25.0
    dx -= (dx > 25.0f) ? 50.0f : ((dx < -25.0f) ? -50.0f : 0.0f);
    dy -= (dy > 25.0f) ? 50.0f : ((dy < -25.0f) ? -50.0f : 0.0f);
    dz -= (dz > 25.0f) ? 50.0f : ((dz < -25.0f) ? -50.0f : 0.0f);
    float r2 = dx * dx + dy * dy + dz * dz;
    float rs = __builtin_amdgcn_rsqf(fmaxf(r2, 1e-24f));   // ~1ulp v_rsq_f32
    float r  = r2 * rs;                                    // r = sqrt(r2)
    float t  = (r - r0) * inv_dr;
    t = fminf(fmaxf(t, 0.0f), 1023.0f);
    int idx = min((int)t, N_TABLE - 2);
    float frac = t - (float)idx;
    float sm = (tfa[idx] + frac * tfd[idx]) * rs;          // fm / r
    fx += sm * dx; fy += sm * dy; fz += sm * dz;
}

// ---------------- K4: reduce via counting sort + balanced segment walk ----------------
// sorted[] holds full entries. Each thread owns an equal contiguous slice of the
// sorted array (<=18 entries), accumulates per-run in registers, flushes to
// pacc[local] only on run change (~1.25 flushes/segment, rare LDS atomics).
// 6-deep gather batches for MLP. No ballots, no shfl loops, no hot-loop atomics.
template<int USE_Q4>
__global__ __launch_bounds__(RED_THREADS) void reduce_sorted_kernel(
    const float* __restrict__ q, const float4* __restrict__ q4,
    const float* __restrict__ table_r, const float* __restrict__ table_f,
    const uint* __restrict__ binBase, const uint* __restrict__ entries,
    float* __restrict__ force, int n_atoms)
{
    __shared__ float tfa[N_TABLE];            // 4 KB
    __shared__ float tfd[N_TABLE];            // 4 KB
    __shared__ uint  sorted[PHASE_CAP];       // 36.9 KB (full entries)
    __shared__ uint  hcnt[128], hcur[128], sscan[128];   // 1.5 KB
    __shared__ float qsx[128], qsy[128], qsz[128];       // 1.5 KB
    __shared__ float paccx[128], paccy[128], paccz[128]; // 1.5 KB

    int b = blockIdx.x, tid = threadIdx.x;
    int atomBase = b << 7;
    if (atomBase >= n_atoms) return;
    int nA = min(128, n_atoms - atomBase);

    const float r0     = table_r[0];
    const float rend   = table_r[N_TABLE - 1];
    const float inv_dr = (float)(N_TABLE - 1) / (rend - r0);

    for (int k = tid; k < N_TABLE - 1; k += RED_THREADS) {
        float a = table_f[k];
        tfa[k] = a; tfd[k] = table_f[k + 1] - a;
    }
    if (tid < 128) {
        paccx[tid] = 0.0f; paccy[tid] = 0.0f; paccz[tid] = 0.0f;
        if (tid < nA) {
            if (USE_Q4) { float4 v = q4[atomBase + tid]; qsx[tid] = v.x; qsy[tid] = v.y; qsz[tid] = v.z; }
            else {
                qsx[tid] = q[(atomBase + tid) * 3];
                qsy[tid] = q[(atomBase + tid) * 3 + 1];
                qsz[tid] = q[(atomBase + tid) * 3 + 2];
            }
        } else { qsx[tid] = 0.0f; qsy[tid] = 0.0f; qsz[tid] = 0.0f; }
    }

    uint e0 = binBase[b], e1 = binBase[b + 1];

    for (uint es = e0; es < e1; es += PHASE_CAP) {
        uint ee  = min(es + PHASE_CAP, e1);
        uint cnt = ee - es;

        if (tid < 128) hcnt[tid] = 0;
        __syncthreads();

        // phase histogram of locals (coalesced global read)
        for (uint e = es + tid; e < ee; e += RED_THREADS)
            atomicAdd(&hcnt[entries[e] & 127u], 1u);
        __syncthreads();

        // 128-wide exclusive scan -> cursors
        if (tid < 128) sscan[tid] = hcnt[tid];
        __syncthreads();
        for (int off = 1; off < 128; off <<= 1) {
            uint t = 0;
            if (tid < 128 && tid >= off) t = sscan[tid - off];
            __syncthreads();
            if (tid < 128) sscan[tid] += t;
            __syncthreads();
        }
        if (tid < 128) hcur[tid] = sscan[tid] - hcnt[tid];
        __syncthreads();

        // counting sort: full entry at sorted position
        for (uint e = es + tid; e < ee; e += RED_THREADS) {
            uint ev = entries[e];
            uint p  = atomicAdd(&hcur[ev & 127u], 1u);
            sorted[p] = ev;
        }
        __syncthreads();

        // balanced segment walk with 6-deep gather batches
        {
            uint seg = (cnt + RED_THREADS - 1) / RED_THREADS;   // <= 18
            uint k0 = min((uint)tid * seg, cnt);
            uint k1 = min(k0 + seg, cnt);
            int curL = -1;
            float fx = 0.0f, fy = 0.0f, fz = 0.0f;
            float sx = 0.0f, sy = 0.0f, sz = 0.0f;

            for (uint k = k0; k < k1; k += 6) {
                uint n = min(6u, k1 - k);
                uint ev[6];
                float gx[6], gy[6], gz[6];
                #pragma unroll
                for (uint t = 0; t < 6; t++)
                    ev[t] = sorted[k + (t < n ? t : 0u)];
                #pragma unroll
                for (uint t = 0; t < 6; t++) {
                    uint o = ev[t] >> 7;
                    if (USE_Q4) { float4 g = q4[o]; gx[t] = g.x; gy[t] = g.y; gz[t] = g.z; }
                    else { gx[t] = q[3 * o]; gy[t] = q[3 * o + 1]; gz[t] = q[3 * o + 2]; }
                }
                #pragma unroll
                for (uint t = 0; t < 6; t++) {
                    if (t < n) {
                        int l = (int)(ev[t] & 127u);
                        if (l != curL) {
                            if (curL >= 0) {
                                atomicAdd(&paccx[curL], fx);
                                atomicAdd(&paccy[curL], fy);
                                atomicAdd(&paccz[curL], fz);
                            }
                            curL = l;
                            sx = qsx[l]; sy = qsy[l]; sz = qsz[l];
                            fx = 0.0f; fy = 0.0f; fz = 0.0f;
                        }
                        phys_acc(sx, sy, sz, gx[t], gy[t], gz[t], tfa, tfd, r0, inv_dr, fx, fy, fz);
                    }
                }
            }
            if (curL >= 0) {
                atomicAdd(&paccx[curL], fx);
                atomicAdd(&paccy[curL], fy);
                atomicAdd(&paccz[curL], fz);
            }
        }
        __syncthreads();   // protect hcnt/sorted/pacc before next phase
    }

    __syncthreads();
    for (int k = tid; k < nA; k += RED_THREADS) {
        force[(atomBase + k) * 3 + 0] = paccx[k];
        force[(atomBase + k) * 3 + 1] = paccy[k];
        force[(atomBase + k) * 3 + 2] = paccz[k];
    }
}

// ---------------- fallback: proven global-atomic kernel ----------------
__global__ __launch_bounds__(THREADS) void pair_force_atomic_kernel(
    const float* __restrict__ q, const int2* __restrict__ nbr,
    const float* __restrict__ table_r, const float* __restrict__ table_f,
    float* __restrict__ force, int n_pairs)
{
    __shared__ float tr[N_TABLE];
    __shared__ float tf[N_TABLE];
    for (int k = threadIdx.x; k < N_TABLE; k += THREADS) { tr[k] = table_r[k]; tf[k] = table_f[k]; }
    __syncthreads();
    const float r0 = tr[0], rend = tr[N_TABLE - 1];
    const float inv_dr = (float)(N_TABLE - 1) / (rend - r0);
    int p = blockIdx.x * THREADS + threadIdx.x;
    if (p >= n_pairs) return;
    int2 ij = nbr[p];
    int i = ij.x, j = ij.y;
    float dx = q[3 * i] - q[3 * j], dy = q[3 * i + 1] - q[3 * j + 1], dz = q[3 * i + 2] - q[3 * j + 2];
    dx -= CELL * rintf(dx / CELL); dy -= CELL * rintf(dy / CELL); dz -= CELL * rintf(dz / CELL);
    float r = sqrtf(dx * dx + dy * dy + dz * dz);
    float inv = 1.0f / fmaxf(r, 1e-12f);
    float fm;
    if (r <= r0) fm = tf[0];
    else if (r >= rend) fm = tf[N_TABLE - 1];
    else {
        float t = (r - r0) * inv_dr;
        int idx = min(max((int)t, 0), N_TABLE - 2);
        if (r < tr[idx]) idx = max(idx - 1, 0);
        else if (r >= tr[idx + 1]) idx = min(idx + 1, N_TABLE - 2);
        float rl = tr[idx], rh = tr[idx + 1];
        fm = tf[idx] + (r - rl) * (tf[idx + 1] - tf[idx]) / (rh - rl);
    }
    float s = fm * inv;
    float fx = s * dx, fy = s * dy, fz = s * dz;
    atomicAdd(&force[3 * i + 0], fx); atomicAdd(&force[3 * i + 1], fy); atomicAdd(&force[3 * i + 2], fz);
    atomicAdd(&force[3 * j + 0], -fx); atomicAdd(&force[3 * j + 1], -fy); atomicAdd(&force[3 * j + 2], -fz);
}

extern "C" void kernel_launch(void* const* d_in, const int* in_sizes, int n_in,
                              void* d_out, int out_size, void* d_ws, size_t ws_size,
                              hipStream_t stream) {
    const float* q       = (const float*)d_in[0];
    const int2*  nbr     = (const int2*)d_in[1];
    const float* table_r = (const float*)d_in[2];
    const float* table_f = (const float*)d_in[3];
    float*       force   = (float*)d_out;

    const int n_pairs = in_sizes[1] / 2;
    const int n_atoms = in_sizes[0] / 3;

    // workspace layout (256B-aligned)
    size_t off_partial  = 0;
    size_t off_rawh     = (off_partial + (size_t)NB * NBLK * 4 + 255) & ~255ull;   // 2 MB
    size_t off_binTotal = (off_rawh + (size_t)NB * NBLK * 4 + 255) & ~255ull;      // +2 MB
    size_t off_binBase  = (off_binTotal + (size_t)NB * 4 + 255) & ~255ull;
    size_t off_entries  = (off_binBase + (size_t)(NB + 1) * 4 + 255) & ~255ull;
    size_t off_q4       = (off_entries + (size_t)2 * n_pairs * 4 + 255) & ~255ull;
    size_t need_base    = off_q4;                       // without q4
    size_t need_q4      = off_q4 + (size_t)n_atoms * 16;

    if (ws_size < need_base || n_atoms > NB * 128) {
        hipMemsetAsync(d_out, 0, (size_t)out_size * sizeof(float), stream);
        int blocks = (n_pairs + THREADS - 1) / THREADS;
        pair_force_atomic_kernel<<<blocks, THREADS, 0, stream>>>(q, nbr, table_r, table_f, force, n_pairs);
        return;
    }

    char* ws = (char*)d_ws;
    uint*   partial  = (uint*)(ws + off_partial);
    uint*   rawh     = (uint*)(ws + off_rawh);
    uint*   binTotal = (uint*)(ws + off_binTotal);
    uint*   binBase  = (uint*)(ws + off_binBase);
    uint*   entries  = (uint*)(ws + off_entries);
    float4* q4       = (float4*)(ws + off_q4);
    int use_q4 = (ws_size >= need_q4) ? 1 : 0;

    int ppb = (((n_pairs + NBLK - 1) / NBLK) + 1) & ~1;   // even pairs per block

    if (use_q4) {
        int pb = (n_atoms + THREADS - 1) / THREADS;
        pack_q4_kernel<<<pb, THREADS, 0, stream>>>(q, q4, n_atoms);
    }
    hist_kernel<<<NBLK, THREADS, 0, stream>>>(nbr, partial, rawh, n_pairs, ppb);
    scan_rows_kernel<<<NB, THREADS, 0, stream>>>(partial, binTotal);
    scan_totals_kernel<<<1, THREADS, 0, stream>>>(binTotal, binBase);
    if (2 * ppb <= LBUF_CAP)
        scatter_sorted_kernel<<<NBLK, SCAT_THREADS, 0, stream>>>(
            nbr, rawh, partial, binBase, entries, n_pairs, ppb);
    else
        scatter_plain_kernel<<<NBLK, THREADS, 0, stream>>>(
            nbr, partial, binBase, entries, n_pairs, ppb);
    if (use_q4)
        reduce_sorted_kernel<1><<<NB, RED_THREADS, 0, stream>>>(q, q4, table_r, table_f, binBase, entries, force, n_atoms);
    else
        reduce_sorted_kernel<0><<<NB, RED_THREADS, 0, stream>>>(q, q4, table_r, table_f, binBase, entries, force, n_atoms);
}

// Round 17
// 156.253 us; speedup vs baseline: 1.2397x; 1.2397x over previous
//
#include <hip/hip_runtime.h>

#define CELL 50.0f
#define N_TABLE 1024
#define NB 1024            // buckets of 128 atoms each (max 131072 atoms)
#define NBLK 512           // histogram/scatter blocks
#define THREADS 256
#define SCAT_THREADS 512
#define LBUF_CAP 25088     // max entries per scatter block (2*ppb)
#define RED_THREADS 512
#define NREP 8             // one acc replica per wave in reduce (REQUIRED: wave-private)
#define BATCH 6            // entries per thread per chunk in reduce

typedef unsigned int uint;
typedef unsigned long long ull;

// ---------------- K0: pack q into float4 ----------------
__global__ __launch_bounds__(THREADS) void pack_q4_kernel(
    const float* __restrict__ q, float4* __restrict__ q4, int n_atoms)
{
    int i = blockIdx.x * THREADS + threadIdx.x;
    if (i < n_atoms)
        q4[i] = make_float4(q[3 * i], q[3 * i + 1], q[3 * i + 2], 0.0f);
}

// ---------------- K1: per-block bucket histogram (int4 loads) ----------------
// Writes BOTH the scan-layout partial[k*NBLK+blk] and raw rawh[blk*NB+k].
__global__ __launch_bounds__(THREADS) void hist_kernel(
    const int2* __restrict__ nbr, uint* __restrict__ partial,
    uint* __restrict__ rawh, int n_pairs, int ppb)
{
    __shared__ uint h[NB];
    for (int k = threadIdx.x; k < NB; k += THREADS) h[k] = 0;
    __syncthreads();
    int start = blockIdx.x * ppb;                 // ppb even -> start even
    int end   = min(start + ppb, n_pairs & ~1);
    const int4* nbr4 = (const int4*)nbr;
    for (int p2 = (start >> 1) + threadIdx.x; p2 < (end >> 1); p2 += THREADS) {
        int4 v = nbr4[p2];
        atomicAdd(&h[((uint)v.x) >> 7], 1u);
        atomicAdd(&h[((uint)v.y) >> 7], 1u);
        atomicAdd(&h[((uint)v.z) >> 7], 1u);
        atomicAdd(&h[((uint)v.w) >> 7], 1u);
    }
    if (blockIdx.x == 0 && threadIdx.x == 0 && (n_pairs & 1)) {
        int2 ij = nbr[n_pairs - 1];
        atomicAdd(&h[((uint)ij.x) >> 7], 1u);
        atomicAdd(&h[((uint)ij.y) >> 7], 1u);
    }
    __syncthreads();
    for (int k = threadIdx.x; k < NB; k += THREADS) {
        uint c = h[k];
        partial[k * NBLK + blockIdx.x] = c;
        rawh[blockIdx.x * NB + k]      = c;
    }
}

// ---------------- K2a: per-bucket exclusive scan over block partials ----------------
__global__ __launch_bounds__(THREADS) void scan_rows_kernel(
    uint* __restrict__ partial, uint* __restrict__ binTotal)
{
    __shared__ uint s[THREADS];
    int bin = blockIdx.x;
    uint running = 0;
    for (int c = 0; c < NBLK / THREADS; c++) {
        int idx = bin * NBLK + c * THREADS + threadIdx.x;
        uint v = partial[idx];
        s[threadIdx.x] = v;
        __syncthreads();
        for (int off = 1; off < THREADS; off <<= 1) {
            uint t = (threadIdx.x >= (uint)off) ? s[threadIdx.x - off] : 0u;
            __syncthreads();
            s[threadIdx.x] += t;
            __syncthreads();
        }
        partial[idx] = running + s[threadIdx.x] - v;   // exclusive within bin
        uint csum = s[THREADS - 1];
        __syncthreads();
        running += csum;
    }
    if (threadIdx.x == 0) binTotal[bin] = running;
}

// ---------------- K2b: exclusive scan of bucket totals ----------------
__global__ __launch_bounds__(THREADS) void scan_totals_kernel(
    const uint* __restrict__ binTotal, uint* __restrict__ binBase)
{
    __shared__ uint s[THREADS];
    uint v[4];
    uint sum = 0;
    int base = threadIdx.x * 4;
    for (int k = 0; k < 4; k++) { v[k] = binTotal[base + k]; sum += v[k]; }
    s[threadIdx.x] = sum;
    __syncthreads();
    for (int off = 1; off < THREADS; off <<= 1) {
        uint t = (threadIdx.x >= (uint)off) ? s[threadIdx.x - off] : 0u;
        __syncthreads();
        s[threadIdx.x] += t;
        __syncthreads();
    }
    uint run = s[threadIdx.x] - sum;
    for (int k = 0; k < 4; k++) { binBase[base + k] = run; run += v[k]; }
    if (threadIdx.x == THREADS - 1) binBase[NB] = run;
}

// ---------------- K3: LDS-sorted scatter (coalesced run writes) ----------------
// Proven R12/R13 structure: gcur prefetch, int4 double-buffer, batched atomics.
// Copy-out now uses 32-lane half-wave groups (runs avg ~24 entries -> halves idle lanes).
__global__ __launch_bounds__(SCAT_THREADS) void scatter_sorted_kernel(
    const int2* __restrict__ nbr, const uint* __restrict__ rawh,
    const uint* __restrict__ partial, const uint* __restrict__ binBase,
    uint* __restrict__ entries, int n_pairs, int ppb)
{
    __shared__ uint lbuf[LBUF_CAP];          // 100.4 KB
    __shared__ uint localBase[NB];           // 4 KB
    __shared__ uint lcur[NB];                // 4 KB
    __shared__ uint gcur[NB];                // 4 KB: prefetched global dst bases
    __shared__ uint ssc[SCAT_THREADS];       // 2 KB

    int tid = threadIdx.x;
    int blk = blockIdx.x;

    // prefetch global copy-out bases early (latency amortized once, 512-wide)
    for (int k = tid; k < NB; k += SCAT_THREADS)
        gcur[k] = binBase[k] + partial[k * NBLK + blk];

    // per-block histogram -> exclusive scan (2 buckets per thread)
    uint v0 = rawh[blk * NB + 2 * tid];
    uint v1 = rawh[blk * NB + 2 * tid + 1];
    uint sum2 = v0 + v1;
    ssc[tid] = sum2;
    __syncthreads();
    for (int off = 1; off < SCAT_THREADS; off <<= 1) {
        uint t = (tid >= off) ? ssc[tid - off] : 0u;
        __syncthreads();
        ssc[tid] += t;
        __syncthreads();
    }
    uint base = ssc[tid] - sum2;
    localBase[2 * tid]     = base;      lcur[2 * tid]     = base;
    localBase[2 * tid + 1] = base + v0; lcur[2 * tid + 1] = base + v0;
    __syncthreads();

    // bin entries into LDS (double-buffered loads, batched atomics)
    int start = blk * ppb;
    int end   = min(start + ppb, n_pairs & ~1);
    const int4* nbr4 = (const int4*)nbr;
    int lim = end >> 1;
    int p2  = (start >> 1) + tid;
    if (p2 < lim) {
        int4 v = nbr4[p2];
        for (;;) {
            int pn = p2 + SCAT_THREADS;
            int4 vnext;
            bool has = pn < lim;
            if (has) vnext = nbr4[pn];
            uint i0 = (uint)v.x, j0 = (uint)v.y, i1 = (uint)v.z, j1 = (uint)v.w;
            uint o0 = atomicAdd(&lcur[i0 >> 7], 1u);
            uint o1 = atomicAdd(&lcur[j0 >> 7], 1u);
            uint o2 = atomicAdd(&lcur[i1 >> 7], 1u);
            uint o3 = atomicAdd(&lcur[j1 >> 7], 1u);
            lbuf[o0] = (j0 << 7) | (i0 & 127u);
            lbuf[o1] = (i0 << 7) | (j0 & 127u);
            lbuf[o2] = (j1 << 7) | (i1 & 127u);
            lbuf[o3] = (i1 << 7) | (j1 & 127u);
            if (!has) break;
            v = vnext; p2 = pn;
        }
    }
    if (blk == 0 && tid == 0 && (n_pairs & 1)) {
        int2 ij = nbr[n_pairs - 1];
        uint i = (uint)ij.x, j = (uint)ij.y;
        uint o;
        o = atomicAdd(&lcur[i >> 7], 1u); lbuf[o] = (j << 7) | (i & 127u);
        o = atomicAdd(&lcur[j >> 7], 1u); lbuf[o] = (i << 7) | (j & 127u);
    }
    __syncthreads();

    // 32-lane-group coalesced copy-out (16 groups/block; runs avg ~24 entries)
    int grp = tid >> 5, lane5 = tid & 31;
    for (int b = grp; b < NB; b += SCAT_THREADS / 32) {
        uint lb  = localBase[b];
        uint cnt = lcur[b] - lb;
        if (!cnt) continue;
        uint gdst = gcur[b];
        for (uint o = lane5; o < cnt; o += 32)
            entries[gdst + o] = lbuf[lb + o];
    }
}

// ---------------- K3-fallback: unsorted scatter (if LBUF too small) ----------------
__global__ __launch_bounds__(THREADS) void scatter_plain_kernel(
    const int2* __restrict__ nbr, const uint* __restrict__ partial,
    const uint* __restrict__ binBase, uint* __restrict__ entries,
    int n_pairs, int ppb)
{
    __shared__ uint cur[NB];
    for (int k = threadIdx.x; k < NB; k += THREADS)
        cur[k] = binBase[k] + partial[k * NBLK + blockIdx.x];
    __syncthreads();
    int start = blockIdx.x * ppb;
    int end   = min(start + ppb, n_pairs & ~1);
    const int4* nbr4 = (const int4*)nbr;
    for (int p2 = (start >> 1) + threadIdx.x; p2 < (end >> 1); p2 += THREADS) {
        int4 v = nbr4[p2];
        uint i0 = (uint)v.x, j0 = (uint)v.y, i1 = (uint)v.z, j1 = (uint)v.w;
        uint p;
        p = atomicAdd(&cur[i0 >> 7], 1u); entries[p] = (j0 << 7) | (i0 & 127u);
        p = atomicAdd(&cur[j0 >> 7], 1u); entries[p] = (i0 << 7) | (j0 & 127u);
        p = atomicAdd(&cur[i1 >> 7], 1u); entries[p] = (j1 << 7) | (i1 & 127u);
        p = atomicAdd(&cur[j1 >> 7], 1u); entries[p] = (i1 << 7) | (j1 & 127u);
    }
    if (blockIdx.x == 0 && threadIdx.x == 0 && (n_pairs & 1)) {
        int2 ij = nbr[n_pairs - 1];
        uint i = (uint)ij.x, j = (uint)ij.y;
        uint p;
        p = atomicAdd(&cur[i >> 7], 1u); entries[p] = (j << 7) | (i & 127u);
        p = atomicAdd(&cur[j >> 7], 1u); entries[p] = (i << 7) | (j & 127u);
    }
}

// ---------------- K4: per-bucket reduce (leader-shfl dedup; split scalar LDS arrays) ----------------
// Proven best (R13: 88 us). Random-index LDS is all b32.
__device__ __forceinline__ void proc_entry(
    uint ev, float ox, float oy, float oz,
    const float* __restrict__ qsx, const float* __restrict__ qsy, const float* __restrict__ qsz,
    const float* __restrict__ tfa, const float* __restrict__ tfd,
    float* __restrict__ accx, float* __restrict__ accy, float* __restrict__ accz,
    float r0, float inv_dr, int lane)
{
    int local = (int)(ev & 127u);
    float dx = qsx[local] - ox, dy = qsy[local] - oy, dz = qsz[local] - oz;
    // exact minimum image for d in (-50,50): round-half-even boundary at +/-25.0
    dx -= (dx > 25.0f) ? 50.0f : ((dx < -25.0f) ? -50.0f : 0.0f);
    dy -= (dy > 25.0f) ? 50.0f : ((dy < -25.0f) ? -50.0f : 0.0f);
    dz -= (dz > 25.0f) ? 50.0f : ((dz < -25.0f) ? -50.0f : 0.0f);
    float r2 = dx * dx + dy * dy + dz * dz;
    float rs = __builtin_amdgcn_rsqf(fmaxf(r2, 1e-24f));   // ~1ulp v_rsq_f32
    float r  = r2 * rs;                                    // r = sqrt(r2)
    float t  = (r - r0) * inv_dr;
    t = fminf(fmaxf(t, 0.0f), 1023.0f);
    int idx = min((int)t, N_TABLE - 2);
    float frac = t - (float)idx;
    float s = (tfa[idx] + frac * tfd[idx]) * rs;           // fm / r
    float fx = s * dx, fy = s * dy, fz = s * dz;

    // 7-bit ballot grouping of `local` within the wave
    ull m64 = __ballot(1);
    #pragma unroll
    for (int b = 0; b < 7; b++) {
        ull bb = __ballot((local >> b) & 1);
        m64 &= ((local >> b) & 1) ? bb : ~bb;
    }
    ull self = 1ull << lane;
    bool leader = ((m64 & (self - 1ull)) == 0ull);
    ull rem = leader ? (m64 & ~self) : 0ull;

    while (__any(rem != 0ull)) {
        int src = rem ? (int)__builtin_ctzll(rem) : lane;
        float px = __shfl(fx, src);
        float py = __shfl(fy, src);
        float pz = __shfl(fz, src);
        if (rem) {
            fx += px; fy += py; fz += pz;
            rem &= rem - 1ull;
        }
    }
    if (leader) {
        accx[local] += fx;
        accy[local] += fy;
        accz[local] += fz;
    }
}

template<int USE_Q4>
__global__ __launch_bounds__(RED_THREADS, 8) void reduce_kernel(
    const float* __restrict__ q, const float4* __restrict__ q4,
    const float* __restrict__ table_r, const float* __restrict__ table_f,
    const uint* __restrict__ binBase, const uint* __restrict__ entries,
    float* __restrict__ force, int n_atoms)
{
    __shared__ float tfa[N_TABLE];            // f[i]            4 KB
    __shared__ float tfd[N_TABLE];            // f[i+1]-f[i]     4 KB
    __shared__ float qsx[128], qsy[128], qsz[128];          // 1.5 KB
    __shared__ float accx_s[NREP * 128];      // wave-private    4 KB
    __shared__ float accy_s[NREP * 128];      //                 4 KB
    __shared__ float accz_s[NREP * 128];      //                 4 KB

    int b = blockIdx.x;
    int atomBase = b << 7;
    if (atomBase >= n_atoms) return;
    int nA = min(128, n_atoms - atomBase);
    int lane = threadIdx.x & 63;

    const float r0     = table_r[0];
    const float rend   = table_r[N_TABLE - 1];
    const float inv_dr = (float)(N_TABLE - 1) / (rend - r0);

    for (int k = threadIdx.x; k < N_TABLE - 1; k += RED_THREADS) {
        float a = table_f[k], c = table_f[k + 1];
        tfa[k] = a; tfd[k] = c - a;
    }
    for (int k = threadIdx.x; k < nA; k += RED_THREADS) {
        if (USE_Q4) {
            float4 v = q4[atomBase + k];
            qsx[k] = v.x; qsy[k] = v.y; qsz[k] = v.z;
        } else {
            qsx[k] = q[(atomBase + k) * 3];
            qsy[k] = q[(atomBase + k) * 3 + 1];
            qsz[k] = q[(atomBase + k) * 3 + 2];
        }
    }
    for (int k = threadIdx.x; k < NREP * 128; k += RED_THREADS) {
        accx_s[k] = 0.0f; accy_s[k] = 0.0f; accz_s[k] = 0.0f;
    }
    __syncthreads();

    int wv = threadIdx.x >> 6;
    float* accx = &accx_s[wv * 128];
    float* accy = &accy_s[wv * 128];
    float* accz = &accz_s[wv * 128];

    uint e0 = binBase[b], e1 = binBase[b + 1];
    uint count = e1 - e0;
    const uint CHUNK = BATCH * RED_THREADS;
    uint nmain = (count / CHUNK) * CHUNK;

    if (nmain) {
        uint v[BATCH];
        #pragma unroll
        for (int k = 0; k < BATCH; k++)
            v[k] = entries[e0 + threadIdx.x + k * RED_THREADS];

        for (uint base = 0; base < nmain; ) {
            float ox[BATCH], oy[BATCH], oz[BATCH];
            #pragma unroll
            for (int k = 0; k < BATCH; k++) {
                uint other = v[k] >> 7;
                if (USE_Q4) {
                    const float* p = (const float*)&q4[other];
                    ox[k] = p[0]; oy[k] = p[1]; oz[k] = p[2];
                } else {
                    ox[k] = q[3 * other]; oy[k] = q[3 * other + 1]; oz[k] = q[3 * other + 2];
                }
            }
            uint base_n = base + CHUNK;
            uint vn[BATCH];
            if (base_n < nmain) {
                #pragma unroll
                for (int k = 0; k < BATCH; k++)
                    vn[k] = entries[e0 + base_n + threadIdx.x + k * RED_THREADS];
            } else {
                #pragma unroll
                for (int k = 0; k < BATCH; k++) vn[k] = 0u;
            }
            #pragma unroll
            for (int k = 0; k < BATCH; k++)
                proc_entry(v[k], ox[k], oy[k], oz[k], qsx, qsy, qsz, tfa, tfd,
                           accx, accy, accz, r0, inv_dr, lane);
            #pragma unroll
            for (int k = 0; k < BATCH; k++) v[k] = vn[k];
            base = base_n;
        }
    }
    // tail
    for (uint e = e0 + nmain + threadIdx.x; e < e1; e += RED_THREADS) {
        uint ev = entries[e];
        uint other = ev >> 7;
        float ox, oy, oz;
        if (USE_Q4) {
            const float* p = (const float*)&q4[other];
            ox = p[0]; oy = p[1]; oz = p[2];
        } else {
            ox = q[3 * other]; oy = q[3 * other + 1]; oz = q[3 * other + 2];
        }
        proc_entry(ev, ox, oy, oz, qsx, qsy, qsz, tfa, tfd,
                   accx, accy, accz, r0, inv_dr, lane);
    }

    __syncthreads();
    for (int k = threadIdx.x; k < nA; k += RED_THREADS) {
        float sx = 0.0f, sy = 0.0f, sz = 0.0f;
        #pragma unroll
        for (int rp = 0; rp < NREP; rp++) {
            sx += accx_s[rp * 128 + k];
            sy += accy_s[rp * 128 + k];
            sz += accz_s[rp * 128 + k];
        }
        force[(atomBase + k) * 3 + 0] = sx;
        force[(atomBase + k) * 3 + 1] = sy;
        force[(atomBase + k) * 3 + 2] = sz;
    }
}

// ---------------- fallback: proven global-atomic kernel ----------------
__global__ __launch_bounds__(THREADS) void pair_force_atomic_kernel(
    const float* __restrict__ q, const int2* __restrict__ nbr,
    const float* __restrict__ table_r, const float* __restrict__ table_f,
    float* __restrict__ force, int n_pairs)
{
    __shared__ float tr[N_TABLE];
    __shared__ float tf[N_TABLE];
    for (int k = threadIdx.x; k < N_TABLE; k += THREADS) { tr[k] = table_r[k]; tf[k] = table_f[k]; }
    __syncthreads();
    const float r0 = tr[0], rend = tr[N_TABLE - 1];
    const float inv_dr = (float)(N_TABLE - 1) / (rend - r0);
    int p = blockIdx.x * THREADS + threadIdx.x;
    if (p >= n_pairs) return;
    int2 ij = nbr[p];
    int i = ij.x, j = ij.y;
    float dx = q[3 * i] - q[3 * j], dy = q[3 * i + 1] - q[3 * j + 1], dz = q[3 * i + 2] - q[3 * j + 2];
    dx -= CELL * rintf(dx / CELL); dy -= CELL * rintf(dy / CELL); dz -= CELL * rintf(dz / CELL);
    float r = sqrtf(dx * dx + dy * dy + dz * dz);
    float inv = 1.0f / fmaxf(r, 1e-12f);
    float fm;
    if (r <= r0) fm = tf[0];
    else if (r >= rend) fm = tf[N_TABLE - 1];
    else {
        float t = (r - r0) * inv_dr;
        int idx = min(max((int)t, 0), N_TABLE - 2);
        if (r < tr[idx]) idx = max(idx - 1, 0);
        else if (r >= tr[idx + 1]) idx = min(idx + 1, N_TABLE - 2);
        float rl = tr[idx], rh = tr[idx + 1];
        fm = tf[idx] + (r - rl) * (tf[idx + 1] - tf[idx]) / (rh - rl);
    }
    float s = fm * inv;
    float fx = s * dx, fy = s * dy, fz = s * dz;
    atomicAdd(&force[3 * i + 0], fx); atomicAdd(&force[3 * i + 1], fy); atomicAdd(&force[3 * i + 2], fz);
    atomicAdd(&force[3 * j + 0], -fx); atomicAdd(&force[3 * j + 1], -fy); atomicAdd(&force[3 * j + 2], -fz);
}

extern "C" void kernel_launch(void* const* d_in, const int* in_sizes, int n_in,
                              void* d_out, int out_size, void* d_ws, size_t ws_size,
                              hipStream_t stream) {
    const float* q       = (const float*)d_in[0];
    const int2*  nbr     = (const int2*)d_in[1];
    const float* table_r = (const float*)d_in[2];
    const float* table_f = (const float*)d_in[3];
    float*       force   = (float*)d_out;

    const int n_pairs = in_sizes[1] / 2;
    const int n_atoms = in_sizes[0] / 3;

    // workspace layout (256B-aligned)
    size_t off_partial  = 0;
    size_t off_rawh     = (off_partial + (size_t)NB * NBLK * 4 + 255) & ~255ull;   // 2 MB
    size_t off_binTotal = (off_rawh + (size_t)NB * NBLK * 4 + 255) & ~255ull;      // +2 MB
    size_t off_binBase  = (off_binTotal + (size_t)NB * 4 + 255) & ~255ull;
    size_t off_entries  = (off_binBase + (size_t)(NB + 1) * 4 + 255) & ~255ull;
    size_t off_q4       = (off_entries + (size_t)2 * n_pairs * 4 + 255) & ~255ull;
    size_t need_base    = off_q4;                       // without q4
    size_t need_q4      = off_q4 + (size_t)n_atoms * 16;

    if (ws_size < need_base || n_atoms > NB * 128) {
        hipMemsetAsync(d_out, 0, (size_t)out_size * sizeof(float), stream);
        int blocks = (n_pairs + THREADS - 1) / THREADS;
        pair_force_atomic_kernel<<<blocks, THREADS, 0, stream>>>(q, nbr, table_r, table_f, force, n_pairs);
        return;
    }

    char* ws = (char*)d_ws;
    uint*   partial  = (uint*)(ws + off_partial);
    uint*   rawh     = (uint*)(ws + off_rawh);
    uint*   binTotal = (uint*)(ws + off_binTotal);
    uint*   binBase  = (uint*)(ws + off_binBase);
    uint*   entries  = (uint*)(ws + off_entries);
    float4* q4       = (float4*)(ws + off_q4);
    int use_q4 = (ws_size >= need_q4) ? 1 : 0;

    int ppb = (((n_pairs + NBLK - 1) / NBLK) + 1) & ~1;   // even pairs per block

    if (use_q4) {
        int pb = (n_atoms + THREADS - 1) / THREADS;
        pack_q4_kernel<<<pb, THREADS, 0, stream>>>(q, q4, n_atoms);
    }
    hist_kernel<<<NBLK, THREADS, 0, stream>>>(nbr, partial, rawh, n_pairs, ppb);
    scan_rows_kernel<<<NB, THREADS, 0, stream>>>(partial, binTotal);
    scan_totals_kernel<<<1, THREADS, 0, stream>>>(binTotal, binBase);
    if (2 * ppb <= LBUF_CAP)
        scatter_sorted_kernel<<<NBLK, SCAT_THREADS, 0, stream>>>(
            nbr, rawh, partial, binBase, entries, n_pairs, ppb);
    else
        scatter_plain_kernel<<<NBLK, THREADS, 0, stream>>>(
            nbr, partial, binBase, entries, n_pairs, ppb);
    if (use_q4)
        reduce_kernel<1><<<NB, RED_THREADS, 0, stream>>>(q, q4, table_r, table_f, binBase, entries, force, n_atoms);
    else
        reduce_kernel<0><<<NB, RED_THREADS, 0, stream>>>(q, q4, table_r, table_f, binBase, entries, force, n_atoms);
}